// Round 6
// baseline (250.110 us; speedup 1.0000x reference)
//
#include <hip/hip_runtime.h>
#include <cstdint>
#include <cstddef>

#define BB 8
#define NN 2048
#define FF 128
#define HH 128
#define SS 2

typedef _Float16 f16x8 __attribute__((ext_vector_type(8)));
typedef _Float16 f16x4 __attribute__((ext_vector_type(4)));
typedef float f32x4 __attribute__((ext_vector_type(4)));

// ---------------------------------------------------------------------------
// prep: h = X@W^T (+Wb) via fp16 MFMA -> h_t[sb][ch][n] f16 (coalesced via LDS
// transpose). si/sj from MFMA accumulators; cross-wave reduce in LDS.
// (unchanged from r5 — passing)
// ---------------------------------------------------------------------------
__global__ __launch_bounds__(256, 2) void prep_kernel(
    const float* __restrict__ X, const float* __restrict__ Ww, const float* __restrict__ Wb,
    const float* __restrict__ ai, const float* __restrict__ aj, const float* __restrict__ ab,
    _Float16* __restrict__ h_t, float* __restrict__ srow, float* __restrict__ scol)
{
    const int s = blockIdx.z, b = blockIdx.y;
    const int n0 = blockIdx.x * 64;
    const int tid = threadIdx.x;
    __shared__ __align__(16) unsigned char smem[51200];
    float* sredI = (float*)(smem + 49152);
    float* sredJ = (float*)(smem + 49152 + 1024);

    {   // stage Xs (fp32 -> f16, swizzled)
        const int r = tid >> 2, fq = tid & 3;
        const float* src = X + ((size_t)b * NN + n0 + r) * FF + fq * 32;
        unsigned char* dst = smem + r * 256;
        const unsigned rs = r & 15;
        #pragma unroll
        for (int k = 0; k < 4; ++k) {
            float4 v0 = *(const float4*)(src + k * 8);
            float4 v1 = *(const float4*)(src + k * 8 + 4);
            f16x8 h;
            h[0]=(_Float16)v0.x; h[1]=(_Float16)v0.y; h[2]=(_Float16)v0.z; h[3]=(_Float16)v0.w;
            h[4]=(_Float16)v1.x; h[5]=(_Float16)v1.y; h[6]=(_Float16)v1.z; h[7]=(_Float16)v1.w;
            *(f16x8*)(dst + (((fq * 4 + k) ^ rs) << 4)) = h;
        }
    }
    {   // stage Wt (fp32 -> f16, swizzled)
        const int ch = tid >> 1, kh8 = (tid & 1) * 8;
        const float* src = Ww + ((size_t)s * HH + ch) * FF + kh8 * 8;
        unsigned char* dst = smem + 16384 + ch * 256;
        const unsigned cs = ch & 15;
        #pragma unroll
        for (int k = 0; k < 8; ++k) {
            float4 v0 = *(const float4*)(src + k * 8);
            float4 v1 = *(const float4*)(src + k * 8 + 4);
            f16x8 h;
            h[0]=(_Float16)v0.x; h[1]=(_Float16)v0.y; h[2]=(_Float16)v0.z; h[3]=(_Float16)v0.w;
            h[4]=(_Float16)v1.x; h[5]=(_Float16)v1.y; h[6]=(_Float16)v1.z; h[7]=(_Float16)v1.w;
            *(f16x8*)(dst + (((kh8 + k) ^ cs) << 4)) = h;
        }
    }
    __syncthreads();

    const int wave = tid >> 6, lane = tid & 63;
    const int lm = lane & 15, lq = lane >> 4;
    f32x4 acc[4][2];
    #pragma unroll
    for (int m = 0; m < 4; ++m)
        #pragma unroll
        for (int n = 0; n < 2; ++n) acc[m][n] = (f32x4){0.f, 0.f, 0.f, 0.f};

    #pragma unroll
    for (int ks = 0; ks < 4; ++ks) {
        f16x8 af[4], bf[2];
        #pragma unroll
        for (int m = 0; m < 4; ++m) {
            int r = m * 16 + lm;
            af[m] = *(const f16x8*)(smem + r * 256 + ((((ks << 2) | lq) ^ (r & 15)) << 4));
        }
        #pragma unroll
        for (int n = 0; n < 2; ++n) {
            int ch = wave * 32 + n * 16 + lm;
            bf[n] = *(const f16x8*)(smem + 16384 + ch * 256 + ((((ks << 2) | lq) ^ (ch & 15)) << 4));
        }
        #pragma unroll
        for (int m = 0; m < 4; ++m)
            #pragma unroll
            for (int n = 0; n < 2; ++n)
                acc[m][n] = __builtin_amdgcn_mfma_f32_16x16x32_f16(af[m], bf[n], acc[m][n], 0, 0, 0);
    }

    const float wb0 = Wb[s * HH + wave * 32 + lm];
    const float wb1 = Wb[s * HH + wave * 32 + 16 + lm];
    const float ai0 = ai[s * HH + wave * 32 + lm];
    const float ai1 = ai[s * HH + wave * 32 + 16 + lm];
    const float aj0 = aj[s * HH + wave * 32 + lm];
    const float aj1 = aj[s * HH + wave * 32 + 16 + lm];
    float pI[4][4], pJ[4][4];
    #pragma unroll
    for (int m = 0; m < 4; ++m)
        #pragma unroll
        for (int r = 0; r < 4; ++r) {
            float h0 = acc[m][0][r] + wb0;
            float h1 = acc[m][1][r] + wb1;
            pI[m][r] = h0 * ai0 + h1 * ai1;
            pJ[m][r] = h0 * aj0 + h1 * aj1;
        }
    #pragma unroll
    for (int st = 1; st < 16; st <<= 1) {
        #pragma unroll
        for (int m = 0; m < 4; ++m)
            #pragma unroll
            for (int r = 0; r < 4; ++r) {
                pI[m][r] += __shfl_xor(pI[m][r], st);
                pJ[m][r] += __shfl_xor(pJ[m][r], st);
            }
    }
    __syncthreads();

    {   // stage h transposed into LDS [128 ch][64 n] f16 (swizzled)
        #pragma unroll
        for (int m = 0; m < 4; ++m)
            #pragma unroll
            for (int n = 0; n < 2; ++n) {
                float wb = n ? wb1 : wb0;
                f16x4 hv;
                #pragma unroll
                for (int r = 0; r < 4; ++r) hv[r] = (_Float16)(acc[m][n][r] + wb);
                int ch = wave * 32 + n * 16 + lm;
                int slot = m * 2 + (lq >> 1);
                *(f16x4*)(smem + ch * 128 + ((slot ^ (ch & 7)) << 4) + (lq & 1) * 8) = hv;
            }
    }
    if (lm == 0) {
        #pragma unroll
        for (int m = 0; m < 4; ++m)
            #pragma unroll
            for (int r = 0; r < 4; ++r) {
                sredI[wave * 64 + m * 16 + lq * 4 + r] = pI[m][r];
                sredJ[wave * 64 + m * 16 + lq * 4 + r] = pJ[m][r];
            }
    }
    __syncthreads();
    {   // coalesced h_t store
        const int ch = tid >> 1, half = tid & 1;
        _Float16* dst = h_t + ((size_t)((s * BB + b) * HH + ch)) * NN + n0 + half * 32;
        const unsigned cs = ch & 7;
        #pragma unroll
        for (int k = 0; k < 4; ++k) {
            f16x8 v = *(const f16x8*)(smem + ch * 128 + (((half * 4 + k) ^ cs) << 4));
            *(f16x8*)(dst + k * 8) = v;
        }
    }
    if (tid < 64) {
        float sI = sredI[tid] + sredI[64 + tid] + sredI[128 + tid] + sredI[192 + tid] + ab[s];
        float sJ = sredJ[tid] + sredJ[64 + tid] + sredJ[128 + tid] + sredJ[192 + tid];
        size_t idx = (size_t)(s * BB + b) * NN + n0 + tid;
        srow[idx] = sI;
        scol[idx] = sJ;
    }
}

// ---------------------------------------------------------------------------
// attn (register-P flash): 512 thr = 8 waves = 4 strips(16r) x 2 ch-halves.
// TM=64, b-PAIR held per wave (geo shared in-register across 2 batches).
// P lives in registers as the MFMA A-fragment (lane computes e exactly for
// its frag slots: row=lane&15, k=(lane>>4)*8+e). Row stats: 2 shfl_xor.
// Defer-max (THR=8) skips acc rescale in the common path.
// h staged in 128-j chunks, double-buffered dynamic LDS (2 x 64KB):
// layout [batch][ch][u of 16B], u XOR (ch&15) -> bank-balanced b128 r/w.
// ONE barrier per chunk (17 total). Grid 256 = 8 (s,bpair)[XCD-pin] x 32.
// ---------------------------------------------------------------------------
__global__ __launch_bounds__(512, 1) void attn_kernel(
    const float* __restrict__ dist, const float* __restrict__ sigmas,
    const float* __restrict__ thr, const _Float16* __restrict__ h_t,
    const float* __restrict__ srow, const float* __restrict__ scol,
    _Float16* __restrict__ Hcat)
{
    extern __shared__ __align__(16) unsigned char smem[];   // 131072 B

    const int bx = blockIdx.x;
    const int grp = bx & 7;                 // (s,bpair) -> XCD pin
    const int i0 = (bx >> 3) * 64;
    const int s = grp >> 2;
    const int b0 = (grp & 3) * 2;

    const int tid = threadIdx.x;
    const int wave = tid >> 6, lane = tid & 63;
    const int lm = lane & 15, lq = lane >> 4;
    const int strip = wave >> 1, chh = wave & 1;

    const float sg = sigmas[s];
    const float inv2s2 = 1.0f / (2.0f * sg * sg);
    const float th = thr[s];

    const int row_g = i0 + strip * 16 + lm;          // e-row this lane owns
    const size_t sb0 = (size_t)(s * BB + b0) * NN;
    const size_t sb1 = sb0 + NN;
    const float si0 = srow[sb0 + row_g];
    const float si1 = srow[sb1 + row_g];
    const float* drow = dist + (size_t)row_g * NN;

    // stage geometry: thread -> (batch, ch, j-half of 128-chunk), 8x16B each
    const int tb = tid >> 8, tch = (tid >> 1) & 127, tjh = tid & 1;
    const _Float16* gsrc = h_t + ((size_t)((s * BB + b0 + tb) * HH + tch)) * NN + tjh * 64;
    const unsigned tsw = tch & 15;

    f32x4 a0[4], a1[4];
    #pragma unroll
    for (int f = 0; f < 4; ++f) { a0[f] = (f32x4){0,0,0,0}; a1[f] = (f32x4){0,0,0,0}; }
    float m0 = -3.0e38f, m1 = -3.0e38f, l0 = 0.f, l1 = 0.f;

    f16x8 st[8];
    float4 dva, dvb, dna, dnb;

#define GLOAD(C) {                                                             \
    const _Float16* g_ = gsrc + (C) * 128;                                     \
    _Pragma("unroll")                                                          \
    for (int k = 0; k < 8; ++k) st[k] = *(const f16x8*)(g_ + k * 8);           \
}
#define LWRITE(C) {                                                            \
    unsigned char* d_ = smem + ((C) & 1) * 65536 + tb * 32768 + tch * 256;     \
    _Pragma("unroll")                                                          \
    for (int k = 0; k < 8; ++k)                                                \
        *(f16x8*)(d_ + ((unsigned)((tjh * 8 + k) ^ tsw) << 4)) = st[k];        \
}

    GLOAD(0); LWRITE(0);
    // dist prefetch for global window 0
    dva = *(const float4*)(drow + lq * 8);
    dvb = *(const float4*)(drow + lq * 8 + 4);
    __syncthreads();

    for (int c = 0; c < 16; ++c) {
        if (c < 15) GLOAD(c + 1);
        const unsigned char* cb = smem + (c & 1) * 65536;

        #pragma unroll
        for (int win = 0; win < 4; ++win) {
            const int gw = c * 4 + win;
            const int jb = gw * 32 + lq * 8;
            {   // prefetch next window's dist (wraps at end; value unused)
                const int jn = ((gw + 1) & 63) * 32 + lq * 8;
                dna = *(const float4*)(drow + jn);
                dnb = *(const float4*)(drow + jn + 4);
            }
            float4 s0a = *(const float4*)(scol + sb0 + jb);
            float4 s0b = *(const float4*)(scol + sb0 + jb + 4);
            float4 s1a = *(const float4*)(scol + sb1 + jb);
            float4 s1b = *(const float4*)(scol + sb1 + jb + 4);

            float e0[8], e1[8];
            #pragma unroll
            for (int k = 0; k < 8; ++k) {
                float d = (k < 4) ? dva[k & 3] : dvb[k & 3];
                float A = __expf(-d * d * inv2s2);
                float den = 1.0f + __expf(-10.0f * (A - th));
                float msk = __builtin_amdgcn_rcpf(den);
                float dd = (jb + k == row_g) ? 1.0f : d;
                float x2 = dd + 1e-5f;
                float ri = __builtin_amdgcn_rcpf(x2);
                ri = ri * (2.0f - x2 * ri);
                float c0 = (k < 4) ? s0a[k & 3] : s0b[k & 3];
                float c1 = (k < 4) ? s1a[k & 3] : s1b[k & 3];
                float t0 = si0 + c0; t0 = fmaxf(t0, 0.1f * t0);
                float t1 = si1 + c1; t1 = fmaxf(t1, 0.1f * t1);
                e0[k] = (t0 + ri) * msk;
                e1[k] = (t1 + ri) * msk;
            }
            dva = dna; dvb = dnb;

            float wm0 = fmaxf(fmaxf(fmaxf(e0[0], e0[1]), fmaxf(e0[2], e0[3])),
                              fmaxf(fmaxf(e0[4], e0[5]), fmaxf(e0[6], e0[7])));
            float wm1 = fmaxf(fmaxf(fmaxf(e1[0], e1[1]), fmaxf(e1[2], e1[3])),
                              fmaxf(fmaxf(e1[4], e1[5]), fmaxf(e1[6], e1[7])));
            wm0 = fmaxf(wm0, __shfl_xor(wm0, 16)); wm0 = fmaxf(wm0, __shfl_xor(wm0, 32));
            wm1 = fmaxf(wm1, __shfl_xor(wm1, 16)); wm1 = fmaxf(wm1, __shfl_xor(wm1, 32));

            if (!__all(wm0 <= m0 + 8.0f)) {       // defer-max rescale (batch 0)
                float mn = fmaxf(m0, wm0);
                float sc = __expf(m0 - mn);
                l0 *= sc;
                #pragma unroll
                for (int r = 0; r < 4; ++r) {
                    float scr = __shfl(sc, lq * 4 + r);
                    a0[0][r] *= scr; a0[1][r] *= scr; a0[2][r] *= scr; a0[3][r] *= scr;
                }
                m0 = mn;
            }
            if (!__all(wm1 <= m1 + 8.0f)) {       // (batch 1)
                float mn = fmaxf(m1, wm1);
                float sc = __expf(m1 - mn);
                l1 *= sc;
                #pragma unroll
                for (int r = 0; r < 4; ++r) {
                    float scr = __shfl(sc, lq * 4 + r);
                    a1[0][r] *= scr; a1[1][r] *= scr; a1[2][r] *= scr; a1[3][r] *= scr;
                }
                m1 = mn;
            }

            f16x8 pa0, pa1;
            float ps0 = 0.f, ps1 = 0.f;
            #pragma unroll
            for (int k = 0; k < 8; ++k) {
                float p0 = __expf(e0[k] - m0); ps0 += p0; pa0[k] = (_Float16)p0;
                float p1 = __expf(e1[k] - m1); ps1 += p1; pa1[k] = (_Float16)p1;
            }
            ps0 += __shfl_xor(ps0, 16); ps0 += __shfl_xor(ps0, 32);
            ps1 += __shfl_xor(ps1, 16); ps1 += __shfl_xor(ps1, 32);
            l0 += ps0; l1 += ps1;

            // MFMA: P (regs) x h (LDS), 4 ch-frags x 2 batches
            #pragma unroll
            for (int f = 0; f < 4; ++f) {
                const int ch = chh * 64 + f * 16 + lm;
                const unsigned ux = ((unsigned)((win * 4 + lq) ^ (ch & 15))) << 4;
                f16x8 bf0 = *(const f16x8*)(cb + ch * 256 + ux);
                f16x8 bf1 = *(const f16x8*)(cb + 32768 + ch * 256 + ux);
                a0[f] = __builtin_amdgcn_mfma_f32_16x16x32_f16(pa0, bf0, a0[f], 0, 0, 0);
                a1[f] = __builtin_amdgcn_mfma_f32_16x16x32_f16(pa1, bf1, a1[f], 0, 0, 0);
            }
        }

        if (c < 15) LWRITE(c + 1);
        __syncthreads();
    }

    // epilogue: /l (shfl broadcast), f16 ebuf in buf0, coalesced store
    float inv0[4], inv1[4];
    #pragma unroll
    for (int r = 0; r < 4; ++r) {
        float lr0 = __shfl(l0, lq * 4 + r);
        float lr1 = __shfl(l1, lq * 4 + r);
        float v0 = __builtin_amdgcn_rcpf(lr0); inv0[r] = v0 * (2.0f - lr0 * v0);
        float v1 = __builtin_amdgcn_rcpf(lr1); inv1[r] = v1 * (2.0f - lr1 * v1);
    }
    _Float16* ebuf = (_Float16*)smem;   // [2b][64 rows][128 ch] f16 = 32KB (buf0)
    #pragma unroll
    for (int f = 0; f < 4; ++f) {
        const int ecol = chh * 64 + f * 16 + lm;
        #pragma unroll
        for (int r = 0; r < 4; ++r) {
            const int erow = strip * 16 + lq * 4 + r;
            ebuf[erow * 128 + ecol]        = (_Float16)(a0[f][r] * inv0[r]);
            ebuf[8192 + erow * 128 + ecol] = (_Float16)(a1[f][r] * inv1[r]);
        }
    }
    __syncthreads();
    {
        const int eb = tid >> 8, er = (tid >> 2) & 63, eq = tid & 3;
        const _Float16* esrc = (const _Float16*)smem + eb * 8192 + er * 128 + eq * 32;
        _Float16* edst = Hcat + ((size_t)((b0 + eb) * NN + i0 + er)) * (SS * HH) + s * HH + eq * 32;
        #pragma unroll
        for (int k = 0; k < 4; ++k)
            *(f16x8*)(edst + k * 8) = *(const f16x8*)(esrc + k * 8);
    }
#undef GLOAD
#undef LWRITE
}

// ---------------------------------------------------------------------------
// fuse: out = Hcat(f16) @ fus_w^T + fus_b via fp16 MFMA. 32-row tiles, K=256.
// (unchanged from r5 — passing)
// ---------------------------------------------------------------------------
__global__ __launch_bounds__(256, 2) void fuse_kernel(
    const _Float16* __restrict__ Hcat, const float* __restrict__ fw,
    const float* __restrict__ fb, float* __restrict__ out)
{
    const int r0 = blockIdx.x * 32;
    const int tid = threadIdx.x;
    __shared__ __align__(16) unsigned char smem[49152];

    {   // stage Hc full K=256 f16
        const int r = tid >> 3, q = tid & 7;
        const _Float16* src = Hcat + (size_t)(r0 + r) * 256 + q * 32;
        unsigned char* dst = smem + r * 512;
        const unsigned rs = r & 7;
        #pragma unroll
        for (int k = 0; k < 4; ++k) {
            f16x8 v = *(const f16x8*)(src + k * 8);
            *(f16x8*)(dst + (((q * 4 + k) ^ rs) << 4)) = v;
        }
    }

    const int wave = tid >> 6, lane = tid & 63;
    const int lm = lane & 15, lq = lane >> 4;
    f32x4 acc[2][2];
    #pragma unroll
    for (int m = 0; m < 2; ++m)
        #pragma unroll
        for (int n = 0; n < 2; ++n) acc[m][n] = (f32x4){0.f, 0.f, 0.f, 0.f};

    for (int c = 0; c < 2; ++c) {
        __syncthreads();
        {   // stage fus_w chunk (fp32->f16)
            const int ch = tid >> 1, kh8 = (tid & 1) * 8;
            const float* src = fw + (size_t)ch * 256 + c * 128 + kh8 * 8;
            unsigned char* dst = smem + 16384 + ch * 256;
            const unsigned cs = ch & 15;
            #pragma unroll
            for (int k = 0; k < 8; ++k) {
                float4 v0 = *(const float4*)(src + k * 8);
                float4 v1 = *(const float4*)(src + k * 8 + 4);
                f16x8 h;
                h[0]=(_Float16)v0.x; h[1]=(_Float16)v0.y; h[2]=(_Float16)v0.z; h[3]=(_Float16)v0.w;
                h[4]=(_Float16)v1.x; h[5]=(_Float16)v1.y; h[6]=(_Float16)v1.z; h[7]=(_Float16)v1.w;
                *(f16x8*)(dst + (((kh8 + k) ^ cs) << 4)) = h;
            }
        }
        __syncthreads();
        #pragma unroll
        for (int ks = 0; ks < 4; ++ks) {
            const int gks = c * 4 + ks;
            f16x8 af[2], bf[2];
            #pragma unroll
            for (int m = 0; m < 2; ++m) {
                int r = m * 16 + lm;
                af[m] = *(const f16x8*)(smem + r * 512 + ((((gks << 2) | lq) ^ (r & 7)) << 4));
            }
            #pragma unroll
            for (int n = 0; n < 2; ++n) {
                int ch = wave * 32 + n * 16 + lm;
                bf[n] = *(const f16x8*)(smem + 16384 + ch * 256 + ((((ks << 2) | lq) ^ (ch & 15)) << 4));
            }
            #pragma unroll
            for (int m = 0; m < 2; ++m)
                #pragma unroll
                for (int n = 0; n < 2; ++n)
                    acc[m][n] = __builtin_amdgcn_mfma_f32_16x16x32_f16(af[m], bf[n], acc[m][n], 0, 0, 0);
        }
    }
    {   // epilogue: + fus_b, fp32 store
        float fb0 = fb[wave * 32 + lm];
        float fb1 = fb[wave * 32 + 16 + lm];
        #pragma unroll
        for (int m = 0; m < 2; ++m)
            #pragma unroll
            for (int n = 0; n < 2; ++n) {
                float fbv = n ? fb1 : fb0;
                int ch = wave * 32 + n * 16 + lm;
                #pragma unroll
                for (int r = 0; r < 4; ++r)
                    out[(size_t)(r0 + m * 16 + lq * 4 + r) * HH + ch] = acc[m][n][r] + fbv;
            }
    }
}

// ---------------------------------------------------------------------------
extern "C" void kernel_launch(void* const* d_in, const int* in_sizes, int n_in,
                              void* d_out, int out_size, void* d_ws, size_t ws_size,
                              hipStream_t stream)
{
    const float* X      = (const float*)d_in[0];
    const float* dist   = (const float*)d_in[1];
    const float* sigmas = (const float*)d_in[2];
    const float* Ww     = (const float*)d_in[3];
    const float* Wb     = (const float*)d_in[4];
    const float* ai     = (const float*)d_in[5];
    const float* aj     = (const float*)d_in[6];
    const float* ab     = (const float*)d_in[7];
    const float* thr    = (const float*)d_in[8];
    const float* fw     = (const float*)d_in[9];
    const float* fb     = (const float*)d_in[10];
    float* out = (float*)d_out;

    // ws layout (~16.3 MB)
    char* ws = (char*)d_ws;
    float*     srow = (float*)(ws);                    // 128 KB
    float*     scol = (float*)(ws + 131072);           // 128 KB
    _Float16*  h_t  = (_Float16*)(ws + 262144);        // 8 MB
    _Float16*  Hcat = (_Float16*)(ws + 8650752);       // 8 MB -> end 17039360

    prep_kernel<<<dim3(NN / 64, BB, SS), 256, 0, stream>>>(X, Ww, Wb, ai, aj, ab, h_t, srow, scol);
    attn_kernel<<<256, 512, 131072, stream>>>(dist, sigmas, thr, h_t, srow, scol, Hcat);
    fuse_kernel<<<BB * NN / 32, 256, 0, stream>>>(Hcat, fw, fb, out);
}

// Round 7
// 191.114 us; speedup vs baseline: 1.3087x; 1.3087x over previous
//
#include <hip/hip_runtime.h>
#include <cstdint>
#include <cstddef>

#define BB 8
#define NN 2048
#define FF 128
#define HH 128
#define SS 2

typedef _Float16 f16x8 __attribute__((ext_vector_type(8)));
typedef _Float16 f16x4 __attribute__((ext_vector_type(4)));
typedef float f32x4 __attribute__((ext_vector_type(4)));

// ---------------------------------------------------------------------------
// geo: g1[s][i][j] = mask (f16), g2[s][i][j] = mask*inv_d (f32, exact div)
// ---------------------------------------------------------------------------
__global__ __launch_bounds__(256) void geo_kernel(
    const float* __restrict__ dist, const float* __restrict__ sigmas,
    const float* __restrict__ thr, _Float16* __restrict__ g1, float* __restrict__ g2)
{
    const size_t idx = ((size_t)blockIdx.x * 256 + threadIdx.x) * 8;
    const int s = (int)(idx >> 22);
    const int i = (int)((idx >> 11) & (NN - 1));
    const int j0 = (int)(idx & (NN - 1));
    const float sg = sigmas[s];
    const float inv2s2 = 1.0f / (2.0f * sg * sg);
    const float th = thr[s];
    const float* dp = dist + (size_t)i * NN + j0;
    float4 d0 = *(const float4*)dp, d1 = *(const float4*)(dp + 4);
    float dv[8] = {d0.x, d0.y, d0.z, d0.w, d1.x, d1.y, d1.z, d1.w};
    f16x8 o1; float og[8];
    #pragma unroll
    for (int k = 0; k < 8; ++k) {
        float d = dv[k];
        float A = __expf(-d * d * inv2s2);
        float msk = 1.0f / (1.0f + __expf(-10.0f * (A - th)));
        float dd = (j0 + k == i) ? 1.0f : d;
        float invd = 1.0f / (dd + 1e-5f);
        o1[k] = (_Float16)msk;
        og[k] = msk * invd;
    }
    *(f16x8*)(g1 + idx) = o1;
    *(float4*)(g2 + idx)     = (float4){og[0], og[1], og[2], og[3]};
    *(float4*)(g2 + idx + 4) = (float4){og[4], og[5], og[6], og[7]};
}

// ---------------------------------------------------------------------------
// prep: h = X@W^T (+Wb) via fp16 MFMA -> h_t[sb][ch][n] f16 (coalesced via LDS
// transpose). si/sj from MFMA accumulators; cross-wave reduce in LDS.
// (unchanged — passing since r5)
// ---------------------------------------------------------------------------
__global__ __launch_bounds__(256, 2) void prep_kernel(
    const float* __restrict__ X, const float* __restrict__ Ww, const float* __restrict__ Wb,
    const float* __restrict__ ai, const float* __restrict__ aj, const float* __restrict__ ab,
    _Float16* __restrict__ h_t, float* __restrict__ srow, float* __restrict__ scol)
{
    const int s = blockIdx.z, b = blockIdx.y;
    const int n0 = blockIdx.x * 64;
    const int tid = threadIdx.x;
    __shared__ __align__(16) unsigned char smem[51200];
    float* sredI = (float*)(smem + 49152);
    float* sredJ = (float*)(smem + 49152 + 1024);

    {   // stage Xs (fp32 -> f16, swizzled)
        const int r = tid >> 2, fq = tid & 3;
        const float* src = X + ((size_t)b * NN + n0 + r) * FF + fq * 32;
        unsigned char* dst = smem + r * 256;
        const unsigned rs = r & 15;
        #pragma unroll
        for (int k = 0; k < 4; ++k) {
            float4 v0 = *(const float4*)(src + k * 8);
            float4 v1 = *(const float4*)(src + k * 8 + 4);
            f16x8 h;
            h[0]=(_Float16)v0.x; h[1]=(_Float16)v0.y; h[2]=(_Float16)v0.z; h[3]=(_Float16)v0.w;
            h[4]=(_Float16)v1.x; h[5]=(_Float16)v1.y; h[6]=(_Float16)v1.z; h[7]=(_Float16)v1.w;
            *(f16x8*)(dst + (((fq * 4 + k) ^ rs) << 4)) = h;
        }
    }
    {   // stage Wt (fp32 -> f16, swizzled)
        const int ch = tid >> 1, kh8 = (tid & 1) * 8;
        const float* src = Ww + ((size_t)s * HH + ch) * FF + kh8 * 8;
        unsigned char* dst = smem + 16384 + ch * 256;
        const unsigned cs = ch & 15;
        #pragma unroll
        for (int k = 0; k < 8; ++k) {
            float4 v0 = *(const float4*)(src + k * 8);
            float4 v1 = *(const float4*)(src + k * 8 + 4);
            f16x8 h;
            h[0]=(_Float16)v0.x; h[1]=(_Float16)v0.y; h[2]=(_Float16)v0.z; h[3]=(_Float16)v0.w;
            h[4]=(_Float16)v1.x; h[5]=(_Float16)v1.y; h[6]=(_Float16)v1.z; h[7]=(_Float16)v1.w;
            *(f16x8*)(dst + (((kh8 + k) ^ cs) << 4)) = h;
        }
    }
    __syncthreads();

    const int wave = tid >> 6, lane = tid & 63;
    const int lm = lane & 15, lq = lane >> 4;
    f32x4 acc[4][2];
    #pragma unroll
    for (int m = 0; m < 4; ++m)
        #pragma unroll
        for (int n = 0; n < 2; ++n) acc[m][n] = (f32x4){0.f, 0.f, 0.f, 0.f};

    #pragma unroll
    for (int ks = 0; ks < 4; ++ks) {
        f16x8 af[4], bf[2];
        #pragma unroll
        for (int m = 0; m < 4; ++m) {
            int r = m * 16 + lm;
            af[m] = *(const f16x8*)(smem + r * 256 + ((((ks << 2) | lq) ^ (r & 15)) << 4));
        }
        #pragma unroll
        for (int n = 0; n < 2; ++n) {
            int ch = wave * 32 + n * 16 + lm;
            bf[n] = *(const f16x8*)(smem + 16384 + ch * 256 + ((((ks << 2) | lq) ^ (ch & 15)) << 4));
        }
        #pragma unroll
        for (int m = 0; m < 4; ++m)
            #pragma unroll
            for (int n = 0; n < 2; ++n)
                acc[m][n] = __builtin_amdgcn_mfma_f32_16x16x32_f16(af[m], bf[n], acc[m][n], 0, 0, 0);
    }

    const float wb0 = Wb[s * HH + wave * 32 + lm];
    const float wb1 = Wb[s * HH + wave * 32 + 16 + lm];
    const float ai0 = ai[s * HH + wave * 32 + lm];
    const float ai1 = ai[s * HH + wave * 32 + 16 + lm];
    const float aj0 = aj[s * HH + wave * 32 + lm];
    const float aj1 = aj[s * HH + wave * 32 + 16 + lm];
    float pI[4][4], pJ[4][4];
    #pragma unroll
    for (int m = 0; m < 4; ++m)
        #pragma unroll
        for (int r = 0; r < 4; ++r) {
            float h0 = acc[m][0][r] + wb0;
            float h1 = acc[m][1][r] + wb1;
            pI[m][r] = h0 * ai0 + h1 * ai1;
            pJ[m][r] = h0 * aj0 + h1 * aj1;
        }
    #pragma unroll
    for (int st = 1; st < 16; st <<= 1) {
        #pragma unroll
        for (int m = 0; m < 4; ++m)
            #pragma unroll
            for (int r = 0; r < 4; ++r) {
                pI[m][r] += __shfl_xor(pI[m][r], st);
                pJ[m][r] += __shfl_xor(pJ[m][r], st);
            }
    }
    __syncthreads();

    {   // stage h transposed into LDS [128 ch][64 n] f16 (swizzled)
        #pragma unroll
        for (int m = 0; m < 4; ++m)
            #pragma unroll
            for (int n = 0; n < 2; ++n) {
                float wb = n ? wb1 : wb0;
                f16x4 hv;
                #pragma unroll
                for (int r = 0; r < 4; ++r) hv[r] = (_Float16)(acc[m][n][r] + wb);
                int ch = wave * 32 + n * 16 + lm;
                int slot = m * 2 + (lq >> 1);
                *(f16x4*)(smem + ch * 128 + ((slot ^ (ch & 7)) << 4) + (lq & 1) * 8) = hv;
            }
    }
    if (lm == 0) {
        #pragma unroll
        for (int m = 0; m < 4; ++m)
            #pragma unroll
            for (int r = 0; r < 4; ++r) {
                sredI[wave * 64 + m * 16 + lq * 4 + r] = pI[m][r];
                sredJ[wave * 64 + m * 16 + lq * 4 + r] = pJ[m][r];
            }
    }
    __syncthreads();
    {   // coalesced h_t store
        const int ch = tid >> 1, half = tid & 1;
        _Float16* dst = h_t + ((size_t)((s * BB + b) * HH + ch)) * NN + n0 + half * 32;
        const unsigned cs = ch & 7;
        #pragma unroll
        for (int k = 0; k < 4; ++k) {
            f16x8 v = *(const f16x8*)(smem + ch * 128 + (((half * 4 + k) ^ cs) << 4));
            *(f16x8*)(dst + k * 8) = v;
        }
    }
    if (tid < 64) {
        float sI = sredI[tid] + sredI[64 + tid] + sredI[128 + tid] + sredI[192 + tid] + ab[s];
        float sJ = sredJ[tid] + sredJ[64 + tid] + sredJ[128 + tid] + sredJ[192 + tid];
        size_t idx = (size_t)(s * BB + b) * NN + n0 + tid;
        srow[idx] = sI;
        scol[idx] = sJ;
    }
}

// ---------------------------------------------------------------------------
// attn: flash with geo tables + b-pair + TM=64. 512 thr = 8 waves =
// (batch of pair) x (ch-quarter). TK=64, 32 iters, 2 barriers/iter.
// Grid 256 = 8 (s,bpair)[= blockIdx&7 -> XCD pin; h panels L2-resident]
// x 32 i-tiles. Phase-1: thread = (row 64, jq 8 of 8 j); e = fmaf(leaky(
// si+sj), g1, g2); 3-stage shfl row-reduce; P f16 -> LDS.
// LDS: P [2][64][128B] @0 (16KB), h [2][128][128B] @16384 (32KB),
// scb @49152 (512B), lrow @49664 (512B). Epilogue ebuf reuses @0 (32KB).
// ---------------------------------------------------------------------------
__global__ __launch_bounds__(512, 4) void attn_kernel(
    const _Float16* __restrict__ g1, const float* __restrict__ g2,
    const _Float16* __restrict__ h_t, const float* __restrict__ srow,
    const float* __restrict__ scol, _Float16* __restrict__ Hcat)
{
    __shared__ __align__(16) unsigned char smem[50176];
    float* scb  = (float*)(smem + 49152);   // [2][64] rescale
    float* lrow = (float*)(smem + 49664);   // [2][64] final l

    const int bx = blockIdx.x;
    const int grp = bx & 7;                 // (s,bpair) -> XCD
    const int i0 = (bx >> 3) * 64;
    const int s = grp >> 2;
    const int b0 = (grp & 3) * 2;

    const int tid = threadIdx.x;
    const int wave = tid >> 6, lane = tid & 63;
    const int lm = lane & 15, lq = lane >> 4;

    // phase-1 geometry: 64 rows x 8 j-groups of 8
    const int row = tid >> 3, jq = tid & 7;
    const int gi = i0 + row;
    const unsigned rsw = row & 7;
    const size_t sb0 = (size_t)(s * BB + b0) * NN;
    const size_t sb1 = sb0 + NN;
    const float si0 = srow[sb0 + gi];
    const float si1 = srow[sb1 + gi];
    const size_t girow = ((size_t)s * NN + gi) * NN;

    // h-stage geometry: (batch, ch, j-half of 64)
    const int tb = tid >> 8, tch = (tid >> 1) & 127, tjh = tid & 1;
    const _Float16* hsrc = h_t + ((size_t)((s * BB + b0 + tb) * HH + tch)) * NN + tjh * 32;
    unsigned char* hdst = smem + 16384 + tb * 16384 + tch * 128;
    const unsigned hsw = tch & 7;

    // MFMA: wave -> (batch of pair, ch-quarter)
    const int wb = wave >> 2, cq = wave & 3;

    f32x4 acc[4][2];
    #pragma unroll
    for (int m = 0; m < 4; ++m)
        #pragma unroll
        for (int n = 0; n < 2; ++n) acc[m][n] = (f32x4){0.f, 0.f, 0.f, 0.f};
    float m0 = -3.0e38f, m1 = -3.0e38f, l0 = 0.f, l1 = 0.f;

    for (int jt = 0; jt < NN / 64; ++jt) {
        const int j0 = jt * 64;
        // issue h loads early (L2 hits; consumed after phase-1 compute)
        f16x8 hv0 = *(const f16x8*)(hsrc + j0);
        f16x8 hv1 = *(const f16x8*)(hsrc + j0 + 8);
        f16x8 hv2 = *(const f16x8*)(hsrc + j0 + 16);
        f16x8 hv3 = *(const f16x8*)(hsrc + j0 + 24);

        // ---------------- phase 1: e for both batches from geo tables
        const int jb = j0 + jq * 8;
        f16x8 gv = *(const f16x8*)(g1 + girow + jb);
        float4 q0 = *(const float4*)(g2 + girow + jb);
        float4 q1 = *(const float4*)(g2 + girow + jb + 4);
        float4 c00 = *(const float4*)(scol + sb0 + jb);
        float4 c01 = *(const float4*)(scol + sb0 + jb + 4);
        float4 c10 = *(const float4*)(scol + sb1 + jb);
        float4 c11 = *(const float4*)(scol + sb1 + jb + 4);

        float e0[8], e1[8];
        #pragma unroll
        for (int k = 0; k < 8; ++k) {
            float gg = (k < 4) ? q0[k & 3] : q1[k & 3];
            float g1f = (float)gv[k];
            float t0 = si0 + ((k < 4) ? c00[k & 3] : c01[k & 3]);
            float t1 = si1 + ((k < 4) ? c10[k & 3] : c11[k & 3]);
            t0 = fmaxf(t0, 0.1f * t0);
            t1 = fmaxf(t1, 0.1f * t1);
            e0[k] = fmaf(t0, g1f, gg);
            e1[k] = fmaf(t1, g1f, gg);
        }
        float wm0 = fmaxf(fmaxf(fmaxf(e0[0], e0[1]), fmaxf(e0[2], e0[3])),
                          fmaxf(fmaxf(e0[4], e0[5]), fmaxf(e0[6], e0[7])));
        float wm1 = fmaxf(fmaxf(fmaxf(e1[0], e1[1]), fmaxf(e1[2], e1[3])),
                          fmaxf(fmaxf(e1[4], e1[5]), fmaxf(e1[6], e1[7])));
        #pragma unroll
        for (int st = 1; st < 8; st <<= 1) {
            wm0 = fmaxf(wm0, __shfl_xor(wm0, st));
            wm1 = fmaxf(wm1, __shfl_xor(wm1, st));
        }
        const float mn0 = fmaxf(m0, wm0), mn1 = fmaxf(m1, wm1);
        const float sc0 = __expf(m0 - mn0), sc1 = __expf(m1 - mn1);
        f16x8 pv0, pv1;
        float ps0 = 0.f, ps1 = 0.f;
        #pragma unroll
        for (int k = 0; k < 8; ++k) {
            float p0 = __expf(e0[k] - mn0); ps0 += p0; pv0[k] = (_Float16)p0;
            float p1 = __expf(e1[k] - mn1); ps1 += p1; pv1[k] = (_Float16)p1;
        }
        #pragma unroll
        for (int st = 1; st < 8; st <<= 1) {
            ps0 += __shfl_xor(ps0, st);
            ps1 += __shfl_xor(ps1, st);
        }
        l0 = l0 * sc0 + ps0; m0 = mn0;
        l1 = l1 * sc1 + ps1; m1 = mn1;
        {
            const unsigned off = row * 128 + ((jq ^ rsw) << 4);
            *(f16x8*)(smem + off) = pv0;
            *(f16x8*)(smem + 8192 + off) = pv1;
        }
        if (jq == 0) { scb[row] = sc0; scb[64 + row] = sc1; }

        // h -> LDS (swizzled chunks)
        *(f16x8*)(hdst + (((tjh * 4 + 0) ^ hsw) << 4)) = hv0;
        *(f16x8*)(hdst + (((tjh * 4 + 1) ^ hsw) << 4)) = hv1;
        *(f16x8*)(hdst + (((tjh * 4 + 2) ^ hsw) << 4)) = hv2;
        *(f16x8*)(hdst + (((tjh * 4 + 3) ^ hsw) << 4)) = hv3;
        __syncthreads();

        // ---------------- MFMA: wave's batch = wb, ch = cq*32..+31
        {
            const unsigned char* Pb = smem + wb * 8192;
            const unsigned char* Hb = smem + 16384 + wb * 16384;
            f16x8 bf[2][2];
            #pragma unroll
            for (int n = 0; n < 2; ++n) {
                const int ch = cq * 32 + n * 16 + lm;
                const unsigned cs = ch & 7;
                bf[n][0] = *(const f16x8*)(Hb + ch * 128 + ((lq ^ cs) << 4));
                bf[n][1] = *(const f16x8*)(Hb + ch * 128 + (((4 | lq) ^ cs) << 4));
            }
            #pragma unroll
            for (int mf = 0; mf < 4; ++mf) {
                const int r = mf * 16 + lm;
                const unsigned sw = r & 7;
                f16x8 a0 = *(const f16x8*)(Pb + r * 128 + ((lq ^ sw) << 4));
                f16x8 a1 = *(const f16x8*)(Pb + r * 128 + (((4 | lq) ^ sw) << 4));
                f32x4 scv = *(const f32x4*)(scb + wb * 64 + mf * 16 + lq * 4);
                #pragma unroll
                for (int n = 0; n < 2; ++n) {
                    acc[mf][n] *= scv;
                    acc[mf][n] = __builtin_amdgcn_mfma_f32_16x16x32_f16(a0, bf[n][0], acc[mf][n], 0, 0, 0);
                    acc[mf][n] = __builtin_amdgcn_mfma_f32_16x16x32_f16(a1, bf[n][1], acc[mf][n], 0, 0, 0);
                }
            }
        }
        __syncthreads();
    }

    if (jq == 0) { lrow[row] = l0; lrow[64 + row] = l1; }
    __syncthreads();

    // epilogue: /l, f16 into ebuf [2][64][128], coalesced store
    _Float16* ebuf = (_Float16*)smem;
    #pragma unroll
    for (int mf = 0; mf < 4; ++mf) {
        f32x4 lv = *(const f32x4*)(lrow + wb * 64 + mf * 16 + lq * 4);
        f32x4 inv;
        #pragma unroll
        for (int r = 0; r < 4; ++r) {
            float x = lv[r];
            float iv = __builtin_amdgcn_rcpf(x);
            inv[r] = iv * (2.0f - x * iv);
        }
        #pragma unroll
        for (int n = 0; n < 2; ++n) {
            const int ecol = cq * 32 + n * 16 + lm;
            #pragma unroll
            for (int r = 0; r < 4; ++r)
                ebuf[wb * 8192 + (mf * 16 + lq * 4 + r) * 128 + ecol] =
                    (_Float16)(acc[mf][n][r] * inv[r]);
        }
    }
    __syncthreads();
    {
        const int eb = tid >> 8, er = (tid >> 2) & 63, eq = tid & 3;
        const _Float16* esrc = (const _Float16*)smem + eb * 8192 + er * 128 + eq * 32;
        _Float16* edst = Hcat + ((size_t)((b0 + eb) * NN + i0 + er)) * (SS * HH) + s * HH + eq * 32;
        #pragma unroll
        for (int k = 0; k < 4; ++k)
            *(f16x8*)(edst + k * 8) = *(const f16x8*)(esrc + k * 8);
    }
}

// ---------------------------------------------------------------------------
// fuse: out = Hcat(f16) @ fus_w^T + fus_b via fp16 MFMA. 32-row tiles, K=256.
// (unchanged — passing since r5)
// ---------------------------------------------------------------------------
__global__ __launch_bounds__(256, 2) void fuse_kernel(
    const _Float16* __restrict__ Hcat, const float* __restrict__ fw,
    const float* __restrict__ fb, float* __restrict__ out)
{
    const int r0 = blockIdx.x * 32;
    const int tid = threadIdx.x;
    __shared__ __align__(16) unsigned char smem[49152];

    {   // stage Hc full K=256 f16
        const int r = tid >> 3, q = tid & 7;
        const _Float16* src = Hcat + (size_t)(r0 + r) * 256 + q * 32;
        unsigned char* dst = smem + r * 512;
        const unsigned rs = r & 7;
        #pragma unroll
        for (int k = 0; k < 4; ++k) {
            f16x8 v = *(const f16x8*)(src + k * 8);
            *(f16x8*)(dst + (((q * 4 + k) ^ rs) << 4)) = v;
        }
    }

    const int wave = tid >> 6, lane = tid & 63;
    const int lm = lane & 15, lq = lane >> 4;
    f32x4 acc[2][2];
    #pragma unroll
    for (int m = 0; m < 2; ++m)
        #pragma unroll
        for (int n = 0; n < 2; ++n) acc[m][n] = (f32x4){0.f, 0.f, 0.f, 0.f};

    for (int c = 0; c < 2; ++c) {
        __syncthreads();
        {   // stage fus_w chunk (fp32->f16)
            const int ch = tid >> 1, kh8 = (tid & 1) * 8;
            const float* src = fw + (size_t)ch * 256 + c * 128 + kh8 * 8;
            unsigned char* dst = smem + 16384 + ch * 256;
            const unsigned cs = ch & 15;
            #pragma unroll
            for (int k = 0; k < 8; ++k) {
                float4 v0 = *(const float4*)(src + k * 8);
                float4 v1 = *(const float4*)(src + k * 8 + 4);
                f16x8 h;
                h[0]=(_Float16)v0.x; h[1]=(_Float16)v0.y; h[2]=(_Float16)v0.z; h[3]=(_Float16)v0.w;
                h[4]=(_Float16)v1.x; h[5]=(_Float16)v1.y; h[6]=(_Float16)v1.z; h[7]=(_Float16)v1.w;
                *(f16x8*)(dst + (((kh8 + k) ^ cs) << 4)) = h;
            }
        }
        __syncthreads();
        #pragma unroll
        for (int ks = 0; ks < 4; ++ks) {
            const int gks = c * 4 + ks;
            f16x8 af[2], bf[2];
            #pragma unroll
            for (int m = 0; m < 2; ++m) {
                int r = m * 16 + lm;
                af[m] = *(const f16x8*)(smem + r * 512 + ((((gks << 2) | lq) ^ (r & 7)) << 4));
            }
            #pragma unroll
            for (int n = 0; n < 2; ++n) {
                int ch = wave * 32 + n * 16 + lm;
                bf[n] = *(const f16x8*)(smem + 16384 + ch * 256 + ((((ks << 2) | lq) ^ (ch & 15)) << 4));
            }
            #pragma unroll
            for (int m = 0; m < 2; ++m)
                #pragma unroll
                for (int n = 0; n < 2; ++n)
                    acc[m][n] = __builtin_amdgcn_mfma_f32_16x16x32_f16(af[m], bf[n], acc[m][n], 0, 0, 0);
        }
    }
    {   // epilogue: + fus_b, fp32 store
        float fb0 = fb[wave * 32 + lm];
        float fb1 = fb[wave * 32 + 16 + lm];
        #pragma unroll
        for (int m = 0; m < 2; ++m)
            #pragma unroll
            for (int n = 0; n < 2; ++n) {
                float fbv = n ? fb1 : fb0;
                int ch = wave * 32 + n * 16 + lm;
                #pragma unroll
                for (int r = 0; r < 4; ++r)
                    out[(size_t)(r0 + m * 16 + lq * 4 + r) * HH + ch] = acc[m][n][r] + fbv;
            }
    }
}

// ---------------------------------------------------------------------------
extern "C" void kernel_launch(void* const* d_in, const int* in_sizes, int n_in,
                              void* d_out, int out_size, void* d_ws, size_t ws_size,
                              hipStream_t stream)
{
    const float* X      = (const float*)d_in[0];
    const float* dist   = (const float*)d_in[1];
    const float* sigmas = (const float*)d_in[2];
    const float* Ww     = (const float*)d_in[3];
    const float* Wb     = (const float*)d_in[4];
    const float* ai     = (const float*)d_in[5];
    const float* aj     = (const float*)d_in[6];
    const float* ab     = (const float*)d_in[7];
    const float* thr    = (const float*)d_in[8];
    const float* fw     = (const float*)d_in[9];
    const float* fb     = (const float*)d_in[10];
    float* out = (float*)d_out;

    // ws layout (67.4 MB; proven available in r2/r3)
    char* ws = (char*)d_ws;
    float*     srow = (float*)(ws);                    // 128 KB
    float*     scol = (float*)(ws + 131072);           // 128 KB
    _Float16*  h_t  = (_Float16*)(ws + 262144);        // 8 MB
    _Float16*  Hcat = (_Float16*)(ws + 8650752);       // 8 MB
    _Float16*  g1   = (_Float16*)(ws + 17039360);      // 16 MB
    float*     g2   = (float*)(ws + 33816576);         // 32 MB -> end 67371008

    geo_kernel<<<(SS * NN * NN / 8) / 256, 256, 0, stream>>>(dist, sigmas, thr, g1, g2);
    prep_kernel<<<dim3(NN / 64, BB, SS), 256, 0, stream>>>(X, Ww, Wb, ai, aj, ab, h_t, srow, scol);
    attn_kernel<<<256, 512, 0, stream>>>(g1, g2, h_t, srow, scol, Hcat);
    fuse_kernel<<<BB * NN / 32, 256, 0, stream>>>(Hcat, fw, fb, out);
}

// Round 9
// 181.189 us; speedup vs baseline: 1.3804x; 1.0548x over previous
//
#include <hip/hip_runtime.h>
#include <cstdint>
#include <cstddef>

#define BB 8
#define NN 2048
#define FF 128
#define HH 128
#define SS 2

typedef _Float16 f16x8 __attribute__((ext_vector_type(8)));
typedef _Float16 f16x4 __attribute__((ext_vector_type(4)));
typedef float f32x4 __attribute__((ext_vector_type(4)));

// ---------------------------------------------------------------------------
// geo: g1[s][i][j] = mask (f16), g2[s][i][j] = mask*inv_d (f32, exact div)
// ---------------------------------------------------------------------------
__global__ __launch_bounds__(256) void geo_kernel(
    const float* __restrict__ dist, const float* __restrict__ sigmas,
    const float* __restrict__ thr, _Float16* __restrict__ g1, float* __restrict__ g2)
{
    const size_t idx = ((size_t)blockIdx.x * 256 + threadIdx.x) * 8;
    const int s = (int)(idx >> 22);
    const int i = (int)((idx >> 11) & (NN - 1));
    const int j0 = (int)(idx & (NN - 1));
    const float sg = sigmas[s];
    const float inv2s2 = 1.0f / (2.0f * sg * sg);
    const float th = thr[s];
    const float* dp = dist + (size_t)i * NN + j0;
    float4 d0 = *(const float4*)dp, d1 = *(const float4*)(dp + 4);
    float dv[8] = {d0.x, d0.y, d0.z, d0.w, d1.x, d1.y, d1.z, d1.w};
    f16x8 o1; float og[8];
    #pragma unroll
    for (int k = 0; k < 8; ++k) {
        float d = dv[k];
        float A = __expf(-d * d * inv2s2);
        float msk = 1.0f / (1.0f + __expf(-10.0f * (A - th)));
        float dd = (j0 + k == i) ? 1.0f : d;
        float invd = 1.0f / (dd + 1e-5f);
        o1[k] = (_Float16)msk;
        og[k] = msk * invd;
    }
    *(f16x8*)(g1 + idx) = o1;
    *(float4*)(g2 + idx)     = (float4){og[0], og[1], og[2], og[3]};
    *(float4*)(g2 + idx + 4) = (float4){og[4], og[5], og[6], og[7]};
}

// ---------------------------------------------------------------------------
// prep: h = X@W^T (+Wb) via fp16 MFMA -> h_t[sb][ch][n] f16. (unchanged)
// ---------------------------------------------------------------------------
__global__ __launch_bounds__(256, 2) void prep_kernel(
    const float* __restrict__ X, const float* __restrict__ Ww, const float* __restrict__ Wb,
    const float* __restrict__ ai, const float* __restrict__ aj, const float* __restrict__ ab,
    _Float16* __restrict__ h_t, float* __restrict__ srow, float* __restrict__ scol)
{
    const int s = blockIdx.z, b = blockIdx.y;
    const int n0 = blockIdx.x * 64;
    const int tid = threadIdx.x;
    __shared__ __align__(16) unsigned char smem[51200];
    float* sredI = (float*)(smem + 49152);
    float* sredJ = (float*)(smem + 49152 + 1024);

    {   // stage Xs (fp32 -> f16, swizzled)
        const int r = tid >> 2, fq = tid & 3;
        const float* src = X + ((size_t)b * NN + n0 + r) * FF + fq * 32;
        unsigned char* dst = smem + r * 256;
        const unsigned rs = r & 15;
        #pragma unroll
        for (int k = 0; k < 4; ++k) {
            float4 v0 = *(const float4*)(src + k * 8);
            float4 v1 = *(const float4*)(src + k * 8 + 4);
            f16x8 h;
            h[0]=(_Float16)v0.x; h[1]=(_Float16)v0.y; h[2]=(_Float16)v0.z; h[3]=(_Float16)v0.w;
            h[4]=(_Float16)v1.x; h[5]=(_Float16)v1.y; h[6]=(_Float16)v1.z; h[7]=(_Float16)v1.w;
            *(f16x8*)(dst + (((fq * 4 + k) ^ rs) << 4)) = h;
        }
    }
    {   // stage Wt (fp32 -> f16, swizzled)
        const int ch = tid >> 1, kh8 = (tid & 1) * 8;
        const float* src = Ww + ((size_t)s * HH + ch) * FF + kh8 * 8;
        unsigned char* dst = smem + 16384 + ch * 256;
        const unsigned cs = ch & 15;
        #pragma unroll
        for (int k = 0; k < 8; ++k) {
            float4 v0 = *(const float4*)(src + k * 8);
            float4 v1 = *(const float4*)(src + k * 8 + 4);
            f16x8 h;
            h[0]=(_Float16)v0.x; h[1]=(_Float16)v0.y; h[2]=(_Float16)v0.z; h[3]=(_Float16)v0.w;
            h[4]=(_Float16)v1.x; h[5]=(_Float16)v1.y; h[6]=(_Float16)v1.z; h[7]=(_Float16)v1.w;
            *(f16x8*)(dst + (((kh8 + k) ^ cs) << 4)) = h;
        }
    }
    __syncthreads();

    const int wave = tid >> 6, lane = tid & 63;
    const int lm = lane & 15, lq = lane >> 4;
    f32x4 acc[4][2];
    #pragma unroll
    for (int m = 0; m < 4; ++m)
        #pragma unroll
        for (int n = 0; n < 2; ++n) acc[m][n] = (f32x4){0.f, 0.f, 0.f, 0.f};

    #pragma unroll
    for (int ks = 0; ks < 4; ++ks) {
        f16x8 af[4], bf[2];
        #pragma unroll
        for (int m = 0; m < 4; ++m) {
            int r = m * 16 + lm;
            af[m] = *(const f16x8*)(smem + r * 256 + ((((ks << 2) | lq) ^ (r & 15)) << 4));
        }
        #pragma unroll
        for (int n = 0; n < 2; ++n) {
            int ch = wave * 32 + n * 16 + lm;
            bf[n] = *(const f16x8*)(smem + 16384 + ch * 256 + ((((ks << 2) | lq) ^ (ch & 15)) << 4));
        }
        #pragma unroll
        for (int m = 0; m < 4; ++m)
            #pragma unroll
            for (int n = 0; n < 2; ++n)
                acc[m][n] = __builtin_amdgcn_mfma_f32_16x16x32_f16(af[m], bf[n], acc[m][n], 0, 0, 0);
    }

    const float wb0 = Wb[s * HH + wave * 32 + lm];
    const float wb1 = Wb[s * HH + wave * 32 + 16 + lm];
    const float ai0 = ai[s * HH + wave * 32 + lm];
    const float ai1 = ai[s * HH + wave * 32 + 16 + lm];
    const float aj0 = aj[s * HH + wave * 32 + lm];
    const float aj1 = aj[s * HH + wave * 32 + 16 + lm];
    float pI[4][4], pJ[4][4];
    #pragma unroll
    for (int m = 0; m < 4; ++m)
        #pragma unroll
        for (int r = 0; r < 4; ++r) {
            float h0 = acc[m][0][r] + wb0;
            float h1 = acc[m][1][r] + wb1;
            pI[m][r] = h0 * ai0 + h1 * ai1;
            pJ[m][r] = h0 * aj0 + h1 * aj1;
        }
    #pragma unroll
    for (int st = 1; st < 16; st <<= 1) {
        #pragma unroll
        for (int m = 0; m < 4; ++m)
            #pragma unroll
            for (int r = 0; r < 4; ++r) {
                pI[m][r] += __shfl_xor(pI[m][r], st);
                pJ[m][r] += __shfl_xor(pJ[m][r], st);
            }
    }
    __syncthreads();

    {   // stage h transposed into LDS [128 ch][64 n] f16 (swizzled)
        #pragma unroll
        for (int m = 0; m < 4; ++m)
            #pragma unroll
            for (int n = 0; n < 2; ++n) {
                float wb = n ? wb1 : wb0;
                f16x4 hv;
                #pragma unroll
                for (int r = 0; r < 4; ++r) hv[r] = (_Float16)(acc[m][n][r] + wb);
                int ch = wave * 32 + n * 16 + lm;
                int slot = m * 2 + (lq >> 1);
                *(f16x4*)(smem + ch * 128 + ((slot ^ (ch & 7)) << 4) + (lq & 1) * 8) = hv;
            }
    }
    if (lm == 0) {
        #pragma unroll
        for (int m = 0; m < 4; ++m)
            #pragma unroll
            for (int r = 0; r < 4; ++r) {
                sredI[wave * 64 + m * 16 + lq * 4 + r] = pI[m][r];
                sredJ[wave * 64 + m * 16 + lq * 4 + r] = pJ[m][r];
            }
    }
    __syncthreads();
    {   // coalesced h_t store
        const int ch = tid >> 1, half = tid & 1;
        _Float16* dst = h_t + ((size_t)((s * BB + b) * HH + ch)) * NN + n0 + half * 32;
        const unsigned cs = ch & 7;
        #pragma unroll
        for (int k = 0; k < 4; ++k) {
            f16x8 v = *(const f16x8*)(smem + ch * 128 + (((half * 4 + k) ^ cs) << 4));
            *(f16x8*)(dst + k * 8) = v;
        }
    }
    if (tid < 64) {
        float sI = sredI[tid] + sredI[64 + tid] + sredI[128 + tid] + sredI[192 + tid] + ab[s];
        float sJ = sredJ[tid] + sredJ[64 + tid] + sredJ[128 + tid] + sredJ[192 + tid];
        size_t idx = (size_t)(s * BB + b) * NN + n0 + tid;
        srow[idx] = sI;
        scol[idx] = sJ;
    }
}

// ---------------------------------------------------------------------------
// attn: flash, geo tables, b-pair, TM=64 — r7 geometry — now 2-stage
// software pipeline: all global loads double-buffered in REGISTERS (1 iter
// ahead), P/h/sc LDS double-buffered, ONE barrier per iter; MFMA(jt-1)
// overlaps phase-1(jt). Grid 256 (1 block/CU), 512 thr, dynamic LDS 99840B:
// P [2buf][2b][64][128B] @0 (32KB), h [2buf][2b][128][128B] @32768 (64KB),
// scb [2buf][2b][64]f @98304 (1KB), lrow [2b][64]f @99328 (512B).
// ---------------------------------------------------------------------------
__global__ __launch_bounds__(512, 2) void attn_kernel(
    const _Float16* __restrict__ g1, const float* __restrict__ g2,
    const _Float16* __restrict__ h_t, const float* __restrict__ srow,
    const float* __restrict__ scol, _Float16* __restrict__ Hcat)
{
    extern __shared__ __align__(16) unsigned char smem[];
    float* scbf = (float*)(smem + 98304);   // [2buf][2b][64]
    float* lrow = (float*)(smem + 99328);   // [2b][64]

    const int bx = blockIdx.x;
    const int grp = bx & 7;                 // (s,bpair) -> XCD
    const int i0 = (bx >> 3) * 64;
    const int s = grp >> 2;
    const int b0 = (grp & 3) * 2;

    const int tid = threadIdx.x;
    const int wave = tid >> 6, lane = tid & 63;
    const int lm = lane & 15, lq = lane >> 4;

    // phase-1 geometry: 64 rows x 8 j-groups of 8
    const int row = tid >> 3, jq = tid & 7;
    const int gi = i0 + row;
    const unsigned rsw = row & 7;
    const size_t sb0 = (size_t)(s * BB + b0) * NN;
    const size_t sb1 = sb0 + NN;
    const float si0 = srow[sb0 + gi];
    const float si1 = srow[sb1 + gi];
    const size_t girow = ((size_t)s * NN + gi) * NN;

    // h-stage geometry
    const int tb = tid >> 8, tch = (tid >> 1) & 127, tjh = tid & 1;
    const _Float16* hsrc = h_t + ((size_t)((s * BB + b0 + tb) * HH + tch)) * NN + tjh * 32;
    const unsigned hsw = tch & 7;

    // MFMA: wave -> (batch of pair, ch-quarter)
    const int wb = wave >> 2, cq = wave & 3;

    f32x4 acc[4][2];
    #pragma unroll
    for (int m = 0; m < 4; ++m)
        #pragma unroll
        for (int n = 0; n < 2; ++n) acc[m][n] = (f32x4){0.f, 0.f, 0.f, 0.f};
    float m0 = -3.0e38f, m1 = -3.0e38f, l0 = 0.f, l1 = 0.f;

    // prefetch register sets
    f16x8 gA, gB, hA0, hA1, hA2, hA3, hB0, hB1, hB2, hB3;
    float4 qA0, qA1, qB0, qB1;
    float4 cA00, cA01, cA10, cA11, cB00, cB01, cB10, cB11;

#define LOADG(G, Q0, Q1, C00, C01, C10, C11, H0, H1, H2, H3, J0) {            \
    const int jb_ = (J0) + jq * 8;                                            \
    G  = *(const f16x8*)(g1 + girow + jb_);                                   \
    Q0 = *(const float4*)(g2 + girow + jb_);                                  \
    Q1 = *(const float4*)(g2 + girow + jb_ + 4);                              \
    C00 = *(const float4*)(scol + sb0 + jb_);                                 \
    C01 = *(const float4*)(scol + sb0 + jb_ + 4);                             \
    C10 = *(const float4*)(scol + sb1 + jb_);                                 \
    C11 = *(const float4*)(scol + sb1 + jb_ + 4);                             \
    H0 = *(const f16x8*)(hsrc + (J0));                                        \
    H1 = *(const f16x8*)(hsrc + (J0) + 8);                                    \
    H2 = *(const f16x8*)(hsrc + (J0) + 16);                                   \
    H3 = *(const f16x8*)(hsrc + (J0) + 24);                                   \
}

#define PHASE1(G, Q0, Q1, C00, C01, C10, C11, H0, H1, H2, H3, PB) {           \
    float e0[8], e1[8];                                                       \
    _Pragma("unroll")                                                         \
    for (int k = 0; k < 8; ++k) {                                             \
        float gg = (k < 4) ? Q0[k & 3] : Q1[k & 3];                           \
        float g1f = (float)G[k];                                              \
        float t0 = si0 + ((k < 4) ? C00[k & 3] : C01[k & 3]);                 \
        float t1 = si1 + ((k < 4) ? C10[k & 3] : C11[k & 3]);                 \
        t0 = fmaxf(t0, 0.1f * t0);                                            \
        t1 = fmaxf(t1, 0.1f * t1);                                            \
        e0[k] = fmaf(t0, g1f, gg);                                            \
        e1[k] = fmaf(t1, g1f, gg);                                            \
    }                                                                         \
    float wm0 = fmaxf(fmaxf(fmaxf(e0[0], e0[1]), fmaxf(e0[2], e0[3])),        \
                      fmaxf(fmaxf(e0[4], e0[5]), fmaxf(e0[6], e0[7])));       \
    float wm1 = fmaxf(fmaxf(fmaxf(e1[0], e1[1]), fmaxf(e1[2], e1[3])),        \
                      fmaxf(fmaxf(e1[4], e1[5]), fmaxf(e1[6], e1[7])));       \
    _Pragma("unroll")                                                         \
    for (int st = 1; st < 8; st <<= 1) {                                      \
        wm0 = fmaxf(wm0, __shfl_xor(wm0, st));                                \
        wm1 = fmaxf(wm1, __shfl_xor(wm1, st));                                \
    }                                                                         \
    const float mn0 = fmaxf(m0, wm0), mn1 = fmaxf(m1, wm1);                   \
    const float sc0 = __expf(m0 - mn0), sc1 = __expf(m1 - mn1);               \
    f16x8 pv0, pv1;                                                           \
    float ps0 = 0.f, ps1 = 0.f;                                               \
    _Pragma("unroll")                                                         \
    for (int k = 0; k < 8; ++k) {                                             \
        float p0 = __expf(e0[k] - mn0); ps0 += p0; pv0[k] = (_Float16)p0;     \
        float p1 = __expf(e1[k] - mn1); ps1 += p1; pv1[k] = (_Float16)p1;     \
    }                                                                         \
    _Pragma("unroll")                                                         \
    for (int st = 1; st < 8; st <<= 1) {                                      \
        ps0 += __shfl_xor(ps0, st);                                           \
        ps1 += __shfl_xor(ps1, st);                                           \
    }                                                                         \
    l0 = l0 * sc0 + ps0; m0 = mn0;                                            \
    l1 = l1 * sc1 + ps1; m1 = mn1;                                            \
    {                                                                         \
        unsigned char* Pd = smem + (PB) * 16384;                              \
        const unsigned off = row * 128 + ((jq ^ rsw) << 4);                   \
        *(f16x8*)(Pd + off) = pv0;                                            \
        *(f16x8*)(Pd + 8192 + off) = pv1;                                     \
    }                                                                         \
    if (jq == 0) { scbf[(PB) * 128 + row] = sc0;                              \
                   scbf[(PB) * 128 + 64 + row] = sc1; }                       \
    {                                                                         \
        unsigned char* hd = smem + 32768 + (PB) * 32768 + tb * 16384 + tch * 128; \
        *(f16x8*)(hd + (((tjh * 4 + 0) ^ hsw) << 4)) = H0;                    \
        *(f16x8*)(hd + (((tjh * 4 + 1) ^ hsw) << 4)) = H1;                    \
        *(f16x8*)(hd + (((tjh * 4 + 2) ^ hsw) << 4)) = H2;                    \
        *(f16x8*)(hd + (((tjh * 4 + 3) ^ hsw) << 4)) = H3;                    \
    }                                                                         \
}

#define MFMA_STEP(MB) {                                                       \
    const unsigned char* Pb = smem + (MB) * 16384 + wb * 8192;                \
    const unsigned char* Hb = smem + 32768 + (MB) * 32768 + wb * 16384;       \
    f16x8 bf[2][2];                                                           \
    _Pragma("unroll")                                                         \
    for (int n = 0; n < 2; ++n) {                                             \
        const int ch = cq * 32 + n * 16 + lm;                                 \
        const unsigned cs = ch & 7;                                           \
        bf[n][0] = *(const f16x8*)(Hb + ch * 128 + ((lq ^ cs) << 4));         \
        bf[n][1] = *(const f16x8*)(Hb + ch * 128 + (((4 | lq) ^ cs) << 4));   \
    }                                                                         \
    _Pragma("unroll")                                                         \
    for (int mf = 0; mf < 4; ++mf) {                                          \
        const int r = mf * 16 + lm;                                           \
        const unsigned sw = r & 7;                                            \
        f16x8 a0 = *(const f16x8*)(Pb + r * 128 + ((lq ^ sw) << 4));          \
        f16x8 a1 = *(const f16x8*)(Pb + r * 128 + (((4 | lq) ^ sw) << 4));    \
        f32x4 scv = *(const f32x4*)(scbf + (MB) * 128 + wb * 64 + mf * 16 + lq * 4); \
        _Pragma("unroll")                                                     \
        for (int n = 0; n < 2; ++n) {                                         \
            acc[mf][n] *= scv;                                                \
            acc[mf][n] = __builtin_amdgcn_mfma_f32_16x16x32_f16(a0, bf[n][0], acc[mf][n], 0, 0, 0); \
            acc[mf][n] = __builtin_amdgcn_mfma_f32_16x16x32_f16(a1, bf[n][1], acc[mf][n], 0, 0, 0); \
        }                                                                     \
    }                                                                         \
}

    LOADG(gA, qA0, qA1, cA00, cA01, cA10, cA11, hA0, hA1, hA2, hA3, 0);
    for (int jt = 0; jt < 32; jt += 2) {
        // even: consume A (buf 0), prefetch B
        LOADG(gB, qB0, qB1, cB00, cB01, cB10, cB11, hB0, hB1, hB2, hB3, (jt + 1) * 64);
        if (jt > 0) MFMA_STEP(1);
        PHASE1(gA, qA0, qA1, cA00, cA01, cA10, cA11, hA0, hA1, hA2, hA3, 0);
        __syncthreads();
        // odd: consume B (buf 1), prefetch A
        if (jt + 2 < 32)
            LOADG(gA, qA0, qA1, cA00, cA01, cA10, cA11, hA0, hA1, hA2, hA3, (jt + 2) * 64);
        MFMA_STEP(0);
        PHASE1(gB, qB0, qB1, cB00, cB01, cB10, cB11, hB0, hB1, hB2, hB3, 1);
        __syncthreads();
    }
    if (jq == 0) { lrow[row] = l0; lrow[64 + row] = l1; }
    MFMA_STEP(1);
    __syncthreads();

    // epilogue: /l, f16 into ebuf [2b][64][128] @0, coalesced store
    _Float16* ebuf = (_Float16*)smem;
    #pragma unroll
    for (int mf = 0; mf < 4; ++mf) {
        f32x4 lv = *(const f32x4*)(lrow + wb * 64 + mf * 16 + lq * 4);
        f32x4 inv;
        #pragma unroll
        for (int r = 0; r < 4; ++r) {
            float x = lv[r];
            float iv = __builtin_amdgcn_rcpf(x);
            inv[r] = iv * (2.0f - x * iv);
        }
        #pragma unroll
        for (int n = 0; n < 2; ++n) {
            const int ecol = cq * 32 + n * 16 + lm;
            #pragma unroll
            for (int r = 0; r < 4; ++r)
                ebuf[wb * 8192 + (mf * 16 + lq * 4 + r) * 128 + ecol] =
                    (_Float16)(acc[mf][n][r] * inv[r]);
        }
    }
    __syncthreads();
    {
        const int eb = tid >> 8, er = (tid >> 2) & 63, eq = tid & 3;
        const _Float16* esrc = (const _Float16*)smem + eb * 8192 + er * 128 + eq * 32;
        _Float16* edst = Hcat + ((size_t)((b0 + eb) * NN + i0 + er)) * (SS * HH) + s * HH + eq * 32;
        #pragma unroll
        for (int k = 0; k < 4; ++k)
            *(f16x8*)(edst + k * 8) = *(const f16x8*)(esrc + k * 8);
    }
#undef LOADG
#undef PHASE1
#undef MFMA_STEP
}

// ---------------------------------------------------------------------------
// fuse: out = Hcat(f16) @ fus_w^T + fus_b via fp16 MFMA. (unchanged)
// ---------------------------------------------------------------------------
__global__ __launch_bounds__(256, 2) void fuse_kernel(
    const _Float16* __restrict__ Hcat, const float* __restrict__ fw,
    const float* __restrict__ fb, float* __restrict__ out)
{
    const int r0 = blockIdx.x * 32;
    const int tid = threadIdx.x;
    __shared__ __align__(16) unsigned char smem[49152];

    {   // stage Hc full K=256 f16
        const int r = tid >> 3, q = tid & 7;
        const _Float16* src = Hcat + (size_t)(r0 + r) * 256 + q * 32;
        unsigned char* dst = smem + r * 512;
        const unsigned rs = r & 7;
        #pragma unroll
        for (int k = 0; k < 4; ++k) {
            f16x8 v = *(const f16x8*)(src + k * 8);
            *(f16x8*)(dst + (((q * 4 + k) ^ rs) << 4)) = v;
        }
    }

    const int wave = tid >> 6, lane = tid & 63;
    const int lm = lane & 15, lq = lane >> 4;
    f32x4 acc[2][2];
    #pragma unroll
    for (int m = 0; m < 2; ++m)
        #pragma unroll
        for (int n = 0; n < 2; ++n) acc[m][n] = (f32x4){0.f, 0.f, 0.f, 0.f};

    for (int c = 0; c < 2; ++c) {
        __syncthreads();
        {   // stage fus_w chunk (fp32->f16)
            const int ch = tid >> 1, kh8 = (tid & 1) * 8;
            const float* src = fw + (size_t)ch * 256 + c * 128 + kh8 * 8;
            unsigned char* dst = smem + 16384 + ch * 256;
            const unsigned cs = ch & 15;
            #pragma unroll
            for (int k = 0; k < 8; ++k) {
                float4 v0 = *(const float4*)(src + k * 8);
                float4 v1 = *(const float4*)(src + k * 8 + 4);
                f16x8 h;
                h[0]=(_Float16)v0.x; h[1]=(_Float16)v0.y; h[2]=(_Float16)v0.z; h[3]=(_Float16)v0.w;
                h[4]=(_Float16)v1.x; h[5]=(_Float16)v1.y; h[6]=(_Float16)v1.z; h[7]=(_Float16)v1.w;
                *(f16x8*)(dst + (((kh8 + k) ^ cs) << 4)) = h;
            }
        }
        __syncthreads();
        #pragma unroll
        for (int ks = 0; ks < 4; ++ks) {
            const int gks = c * 4 + ks;
            f16x8 af[2], bf[2];
            #pragma unroll
            for (int m = 0; m < 2; ++m) {
                int r = m * 16 + lm;
                af[m] = *(const f16x8*)(smem + r * 512 + ((((gks << 2) | lq) ^ (r & 7)) << 4));
            }
            #pragma unroll
            for (int n = 0; n < 2; ++n) {
                int ch = wave * 32 + n * 16 + lm;
                bf[n] = *(const f16x8*)(smem + 16384 + ch * 256 + ((((ks << 2) | lq) ^ (ch & 15)) << 4));
            }
            #pragma unroll
            for (int m = 0; m < 2; ++m)
                #pragma unroll
                for (int n = 0; n < 2; ++n)
                    acc[m][n] = __builtin_amdgcn_mfma_f32_16x16x32_f16(af[m], bf[n], acc[m][n], 0, 0, 0);
        }
    }
    {   // epilogue: + fus_b, fp32 store
        float fb0 = fb[wave * 32 + lm];
        float fb1 = fb[wave * 32 + 16 + lm];
        #pragma unroll
        for (int m = 0; m < 2; ++m)
            #pragma unroll
            for (int n = 0; n < 2; ++n) {
                float fbv = n ? fb1 : fb0;
                int ch = wave * 32 + n * 16 + lm;
                #pragma unroll
                for (int r = 0; r < 4; ++r)
                    out[(size_t)(r0 + m * 16 + lq * 4 + r) * HH + ch] = acc[m][n][r] + fbv;
            }
    }
}

// ---------------------------------------------------------------------------
extern "C" void kernel_launch(void* const* d_in, const int* in_sizes, int n_in,
                              void* d_out, int out_size, void* d_ws, size_t ws_size,
                              hipStream_t stream)
{
    const float* X      = (const float*)d_in[0];
    const float* dist   = (const float*)d_in[1];
    const float* sigmas = (const float*)d_in[2];
    const float* Ww     = (const float*)d_in[3];
    const float* Wb     = (const float*)d_in[4];
    const float* ai     = (const float*)d_in[5];
    const float* aj     = (const float*)d_in[6];
    const float* ab     = (const float*)d_in[7];
    const float* thr    = (const float*)d_in[8];
    const float* fw     = (const float*)d_in[9];
    const float* fb     = (const float*)d_in[10];
    float* out = (float*)d_out;

    // ws layout (67.4 MB)
    char* ws = (char*)d_ws;
    float*     srow = (float*)(ws);                    // 128 KB
    float*     scol = (float*)(ws + 131072);           // 128 KB
    _Float16*  h_t  = (_Float16*)(ws + 262144);        // 8 MB
    _Float16*  Hcat = (_Float16*)(ws + 8650752);       // 8 MB
    _Float16*  g1   = (_Float16*)(ws + 17039360);      // 16 MB
    float*     g2   = (float*)(ws + 33816576);         // 32 MB -> end 67371008

    geo_kernel<<<(SS * NN * NN / 8) / 256, 256, 0, stream>>>(dist, sigmas, thr, g1, g2);
    prep_kernel<<<dim3(NN / 64, BB, SS), 256, 0, stream>>>(X, Ww, Wb, ai, aj, ab, h_t, srow, scol);
    attn_kernel<<<256, 512, 99840, stream>>>(g1, g2, h_t, srow, scol, Hcat);
    fuse_kernel<<<BB * NN / 32, 256, 0, stream>>>(Hcat, fw, fb, out);
}